// Round 1
// baseline (230.463 us; speedup 1.0000x reference)
//
#include <hip/hip_runtime.h>
#include <hip/hip_bf16.h>
#include <stdint.h>

#define HIDDEN 128

typedef __attribute__((ext_vector_type(8))) short short8;
typedef __attribute__((ext_vector_type(4))) float float4v;

static __device__ __forceinline__ unsigned short f2bf(float f) {
    union { float f; unsigned u; } v; v.f = f;
    unsigned r = (v.u + 0x7FFFu + ((v.u >> 16) & 1u)) >> 16;
    return (unsigned short)r;
}
static __device__ __forceinline__ float bf2f(unsigned short h) {
    union { unsigned u; float f; } v; v.u = ((unsigned)h) << 16;
    return v.f;
}

// Kernel 1: Wt[j][k] = combined-W^T in bf16.
// Combined W[k][j]: j<128 -> W1[k*128+j] ; j>=128 -> W1[(128+k)*128 + (j-128)]
// Wt[j*128+k] = W[k][j]  (contiguous in k for MFMA B-fragment loads)
__global__ void prep_wt(const float* __restrict__ W1, unsigned short* __restrict__ Wt) {
    int idx = blockIdx.x * blockDim.x + threadIdx.x;   // 0 .. 32767
    if (idx >= 256 * 128) return;
    int j = idx >> 7, k = idx & 127;
    float v = (j < 128) ? W1[k * 128 + j] : W1[(128 + k) * 128 + (j - 128)];
    Wt[idx] = f2bf(v);
}

// Kernel 2: P[node][0:256] = z[node] @ W  (bf16 out), via mfma_f32_16x16x32_bf16.
// Wave: 16 nodes x 64 cols (4 col-tiles). Block: 4 waves = 64 nodes. grid.y covers 256 cols.
__global__ __launch_bounds__(256) void node_gemm(
        const float* __restrict__ z, const unsigned short* __restrict__ Wt,
        unsigned short* __restrict__ P, int n_nodes) {
    int lane = threadIdx.x & 63;
    int wave = threadIdx.x >> 6;
    int m = lane & 15;
    int quad = lane >> 4;
    int nodebase = blockIdx.x * 64 + wave * 16;
    int colbase  = blockIdx.y * 64;
    int row = nodebase + m;

    // A fragments: lane holds A[m = lane&15][k = quad*8 + j], 4 k-steps of 32
    short8 a[4];
    if (row < n_nodes) {
        const float* zp = z + (size_t)row * HIDDEN;
        #pragma unroll
        for (int s = 0; s < 4; ++s) {
            int k0 = s * 32 + quad * 8;
            float4v z0 = *(const float4v*)(zp + k0);
            float4v z1 = *(const float4v*)(zp + k0 + 4);
            short8 t;
            t[0] = (short)f2bf(z0[0]); t[1] = (short)f2bf(z0[1]);
            t[2] = (short)f2bf(z0[2]); t[3] = (short)f2bf(z0[3]);
            t[4] = (short)f2bf(z1[0]); t[5] = (short)f2bf(z1[1]);
            t[6] = (short)f2bf(z1[2]); t[7] = (short)f2bf(z1[3]);
            a[s] = t;
        }
    } else {
        #pragma unroll
        for (int s = 0; s < 4; ++s) a[s] = (short8)(0);
    }

    float4v acc[4];
    #pragma unroll
    for (int t = 0; t < 4; ++t) acc[t] = (float4v)(0.0f);

    #pragma unroll
    for (int t = 0; t < 4; ++t) {
        int col = colbase + t * 16 + m;           // B: lane holds B[k=quad*8+j][n=lane&15]
        const unsigned short* wp = Wt + (size_t)col * HIDDEN;
        #pragma unroll
        for (int s = 0; s < 4; ++s) {
            short8 b = *(const short8*)(wp + s * 32 + quad * 8);
            acc[t] = __builtin_amdgcn_mfma_f32_16x16x32_bf16(a[s], b, acc[t], 0, 0, 0);
        }
    }

    // C/D layout: col = lane&15, row = quad*4 + reg
    #pragma unroll
    for (int t = 0; t < 4; ++t) {
        #pragma unroll
        for (int r = 0; r < 4; ++r) {
            int node = nodebase + quad * 4 + r;
            if (node < n_nodes)
                P[(size_t)node * 256 + colbase + t * 16 + m] = f2bf(acc[t][r]);
        }
    }
}

// Kernel 3: per edge e: out[e] = sum_j relu(P[row][j] + P[col][128+j] + b1[j]) * W2[j] + b2
// 16 lanes per edge, 8 features per lane (one dwordx4 per gather row per lane-group).
__global__ __launch_bounds__(256) void edge_kernel(
        const int* __restrict__ eli, const unsigned short* __restrict__ P,
        const float* __restrict__ b1, const float* __restrict__ W2,
        const float* __restrict__ b2, float* __restrict__ out, int E) {
    int g      = threadIdx.x >> 4;   // edge slot in block (0..15)
    int lane16 = threadIdx.x & 15;
    int e = blockIdx.x * 16 + g;
    if (e >= E) return;

    int r = eli[e];
    int c = eli[E + e];
    int j0 = lane16 * 8;

    short8 u1 = *(const short8*)(P + (size_t)r * 256 + j0);
    short8 u2 = *(const short8*)(P + (size_t)c * 256 + 128 + j0);
    float4v bA = *(const float4v*)(b1 + j0);
    float4v bB = *(const float4v*)(b1 + j0 + 4);
    float4v wA = *(const float4v*)(W2 + j0);
    float4v wB = *(const float4v*)(W2 + j0 + 4);

    float acc = 0.0f;
    #pragma unroll
    for (int i = 0; i < 4; ++i) {
        float v = bf2f((unsigned short)u1[i]) + bf2f((unsigned short)u2[i]) + bA[i];
        v = fmaxf(v, 0.0f);
        acc = fmaf(v, wA[i], acc);
    }
    #pragma unroll
    for (int i = 0; i < 4; ++i) {
        float v = bf2f((unsigned short)u1[4 + i]) + bf2f((unsigned short)u2[4 + i]) + bB[i];
        v = fmaxf(v, 0.0f);
        acc = fmaf(v, wB[i], acc);
    }

    // reduce across the 16-lane group
    acc += __shfl_xor(acc, 1);
    acc += __shfl_xor(acc, 2);
    acc += __shfl_xor(acc, 4);
    acc += __shfl_xor(acc, 8);

    if (lane16 == 0) out[e] = acc + b2[0];
}

extern "C" void kernel_launch(void* const* d_in, const int* in_sizes, int n_in,
                              void* d_out, int out_size, void* d_ws, size_t ws_size,
                              hipStream_t stream) {
    const float* z  = (const float*)d_in[0];
    const int*   eli = (const int*)d_in[1];
    const float* W1 = (const float*)d_in[2];
    const float* b1 = (const float*)d_in[3];
    const float* W2 = (const float*)d_in[4];
    const float* b2 = (const float*)d_in[5];
    int n_nodes = in_sizes[0] / HIDDEN;       // 100000
    int E       = in_sizes[1] / 2;            // 1000000
    float* out  = (float*)d_out;

    unsigned short* P  = (unsigned short*)d_ws;                              // n_nodes*256 bf16
    unsigned short* Wt = (unsigned short*)((char*)d_ws + (size_t)n_nodes * 256 * 2);

    prep_wt<<<128, 256, 0, stream>>>(W1, Wt);

    dim3 g1((n_nodes + 63) / 64, 4);
    node_gemm<<<g1, 256, 0, stream>>>(z, Wt, P, n_nodes);

    edge_kernel<<<(E + 15) / 16, 256, 0, stream>>>(eli, P, b1, W2, b2, out, E);
}

// Round 2
// 218.658 us; speedup vs baseline: 1.0540x; 1.0540x over previous
//
#include <hip/hip_runtime.h>
#include <hip/hip_bf16.h>
#include <stdint.h>

#define HIDDEN 128

typedef __attribute__((ext_vector_type(8))) short short8;
typedef __attribute__((ext_vector_type(4))) float float4v;

static __device__ __forceinline__ unsigned short f2bf(float f) {
    union { float f; unsigned u; } v; v.f = f;
    unsigned r = (v.u + 0x7FFFu + ((v.u >> 16) & 1u)) >> 16;
    return (unsigned short)r;
}
static __device__ __forceinline__ float bf2f(unsigned short h) {
    union { unsigned u; float f; } v; v.u = ((unsigned)h) << 16;
    return v.f;
}

// Kernel 1: build Wt (logical col-major weight, bf16) + permuted b1/W2.
// Logical combined W[k][j]: j<128 -> W1[k*128+j]; j>=128 -> W1[(128+k)*128+(j-128)]
// Wt[j*128+k] = W[k][j]   (contiguous in k for MFMA B-fragment loads)
// Permutation (within each 128-half): physical pp = m*8+tt  <->  logical jj = tt*16+m
__global__ void prep_wt(const float* __restrict__ W1, const float* __restrict__ b1,
                        const float* __restrict__ W2,
                        unsigned short* __restrict__ Wt,
                        float* __restrict__ b1p, float* __restrict__ W2p) {
    int idx = blockIdx.x * blockDim.x + threadIdx.x;   // 0 .. 32767
    if (idx < 256 * 128) {
        int j = idx >> 7, k = idx & 127;
        float v = (j < 128) ? W1[k * 128 + j] : W1[(128 + k) * 128 + (j - 128)];
        Wt[idx] = f2bf(v);
    }
    if (idx < 128) {
        int m = idx >> 3, tt = idx & 7;
        int jj = tt * 16 + m;
        b1p[idx] = b1[jj];
        W2p[idx] = W2[jj];
    }
}

// Kernel 2: Q[node][0:256] = z[node] @ W in bf16, permuted-store layout.
// Wave: 16 nodes x 256 cols (16 col-tiles). Block: 4 waves = 64 nodes.
__global__ __launch_bounds__(256) void node_gemm(
        const float* __restrict__ z, const unsigned short* __restrict__ Wt,
        unsigned short* __restrict__ Q, int n_nodes) {
    int lane = threadIdx.x & 63;
    int wave = threadIdx.x >> 6;
    int m = lane & 15;
    int quad = lane >> 4;
    int nodebase = blockIdx.x * 64 + wave * 16;
    int row = nodebase + m;

    // A fragments: lane holds A[m][k = quad*8 + j], 4 k-steps of 32
    short8 a[4];
    if (row < n_nodes) {
        const float* zp = z + (size_t)row * HIDDEN;
        #pragma unroll
        for (int s = 0; s < 4; ++s) {
            int k0 = s * 32 + quad * 8;
            float4v z0 = *(const float4v*)(zp + k0);
            float4v z1 = *(const float4v*)(zp + k0 + 4);
            short8 t;
            t[0] = (short)f2bf(z0[0]); t[1] = (short)f2bf(z0[1]);
            t[2] = (short)f2bf(z0[2]); t[3] = (short)f2bf(z0[3]);
            t[4] = (short)f2bf(z1[0]); t[5] = (short)f2bf(z1[1]);
            t[6] = (short)f2bf(z1[2]); t[7] = (short)f2bf(z1[3]);
            a[s] = t;
        }
    } else {
        #pragma unroll
        for (int s = 0; s < 4; ++s) a[s] = (short8)(0);
    }

    float4v acc[16];
    #pragma unroll
    for (int t = 0; t < 16; ++t) acc[t] = (float4v)(0.0f);

    #pragma unroll
    for (int t = 0; t < 16; ++t) {
        const unsigned short* wp = Wt + (size_t)(t * 16 + m) * HIDDEN;  // logical col j = t*16+m
        #pragma unroll
        for (int s = 0; s < 4; ++s) {
            short8 b = *(const short8*)(wp + s * 32 + quad * 8);
            acc[t] = __builtin_amdgcn_mfma_f32_16x16x32_bf16(a[s], b, acc[t], 0, 0, 0);
        }
    }

    // C/D layout: logical col = t*16 + (lane&15), node-row = quad*4 + reg.
    // Permuted store: lane's 8 tiles per half are CONTIGUOUS at physical m*8.
    // Per (r, half): 4 quads write 4 dense 256-B segments — fully coalesced.
    #pragma unroll
    for (int r = 0; r < 4; ++r) {
        int node = nodebase + quad * 4 + r;
        if (node < n_nodes) {
            #pragma unroll
            for (int h = 0; h < 2; ++h) {
                short8 pk;
                #pragma unroll
                for (int tt = 0; tt < 8; ++tt)
                    pk[tt] = (short)f2bf(acc[h * 8 + tt][r]);
                *(short8*)(Q + (size_t)node * 256 + h * 128 + m * 8) = pk;
            }
        }
    }
}

// Kernel 3: per edge e: out[e] = sum_pp relu(Q[r][pp] + Q[c][128+pp] + b1p[pp]) * W2p[pp] + b2
// 16 lanes per edge; 4 edges per lane-group to amortize uniform loads.
__global__ __launch_bounds__(256) void edge_kernel(
        const int* __restrict__ eli, const unsigned short* __restrict__ Q,
        const float* __restrict__ b1p, const float* __restrict__ W2p,
        const float* __restrict__ b2, float* __restrict__ out, int E) {
    int g      = threadIdx.x >> 4;   // group in block (0..15)
    int lane16 = threadIdx.x & 15;
    int j0 = lane16 * 8;

    float4v bA = *(const float4v*)(b1p + j0);
    float4v bB = *(const float4v*)(b1p + j0 + 4);
    float4v wA = *(const float4v*)(W2p + j0);
    float4v wB = *(const float4v*)(W2p + j0 + 4);
    float bias2 = b2[0];

    #pragma unroll
    for (int i = 0; i < 4; ++i) {
        int e = blockIdx.x * 64 + i * 16 + g;
        if (e >= E) continue;
        int r = eli[e];
        int c = eli[E + e];

        short8 u1 = *(const short8*)(Q + (size_t)r * 256 + j0);
        short8 u2 = *(const short8*)(Q + (size_t)c * 256 + 128 + j0);

        float acc = 0.0f;
        #pragma unroll
        for (int k = 0; k < 4; ++k) {
            float v = bf2f((unsigned short)u1[k]) + bf2f((unsigned short)u2[k]) + bA[k];
            v = fmaxf(v, 0.0f);
            acc = fmaf(v, wA[k], acc);
        }
        #pragma unroll
        for (int k = 0; k < 4; ++k) {
            float v = bf2f((unsigned short)u1[4 + k]) + bf2f((unsigned short)u2[4 + k]) + bB[k];
            v = fmaxf(v, 0.0f);
            acc = fmaf(v, wB[k], acc);
        }

        acc += __shfl_xor(acc, 1);
        acc += __shfl_xor(acc, 2);
        acc += __shfl_xor(acc, 4);
        acc += __shfl_xor(acc, 8);

        if (lane16 == 0) out[e] = acc + bias2;
    }
}

extern "C" void kernel_launch(void* const* d_in, const int* in_sizes, int n_in,
                              void* d_out, int out_size, void* d_ws, size_t ws_size,
                              hipStream_t stream) {
    const float* z   = (const float*)d_in[0];
    const int*   eli = (const int*)d_in[1];
    const float* W1  = (const float*)d_in[2];
    const float* b1  = (const float*)d_in[3];
    const float* W2  = (const float*)d_in[4];
    const float* b2  = (const float*)d_in[5];
    int n_nodes = in_sizes[0] / HIDDEN;       // 100000
    int E       = in_sizes[1] / 2;            // 1000000
    float* out  = (float*)d_out;

    size_t qbytes = (size_t)n_nodes * 256 * 2;
    unsigned short* Q   = (unsigned short*)d_ws;
    unsigned short* Wt  = (unsigned short*)((char*)d_ws + qbytes);
    float*          b1p = (float*)((char*)d_ws + qbytes + 256 * 128 * 2);
    float*          W2p = b1p + 128;

    prep_wt<<<128, 256, 0, stream>>>(W1, b1, W2, Wt, b1p, W2p);

    node_gemm<<<(n_nodes + 63) / 64, 256, 0, stream>>>(z, Wt, Q, n_nodes);

    edge_kernel<<<(E + 63) / 64, 256, 0, stream>>>(eli, Q, b1p, W2p, b2, out, E);
}

// Round 3
// 193.132 us; speedup vs baseline: 1.1933x; 1.1322x over previous
//
#include <hip/hip_runtime.h>
#include <hip/hip_bf16.h>
#include <stdint.h>

#define HIDDEN 128

typedef __attribute__((ext_vector_type(8))) short short8;
typedef __attribute__((ext_vector_type(4))) short short4v;
typedef __attribute__((ext_vector_type(4))) float float4v;

static __device__ __forceinline__ unsigned short f2bf(float f) {
    union { float f; unsigned u; } v; v.f = f;
    unsigned r = (v.u + 0x7FFFu + ((v.u >> 16) & 1u)) >> 16;
    return (unsigned short)r;
}
static __device__ __forceinline__ float bf2f(unsigned short h) {
    union { unsigned u; float f; } v; v.u = ((unsigned)h) << 16;
    return v.f;
}

// Kernel 1: build Wt (logical col-major weight, bf16) + permuted b1/W2.
// Logical combined W[k][j]: j<128 -> W1[k*128+j]; j>=128 -> W1[(128+k)*128+(j-128)]
// Wt[j*128+k] = W[k][j]   (contiguous in k for MFMA B-fragment loads)
// Permutation (within each 128-half): physical pp = m*8+tt  <->  logical jj = tt*16+m
__global__ void prep_wt(const float* __restrict__ W1, const float* __restrict__ b1,
                        const float* __restrict__ W2,
                        unsigned short* __restrict__ Wt,
                        float* __restrict__ b1p, float* __restrict__ W2p) {
    int idx = blockIdx.x * blockDim.x + threadIdx.x;   // 0 .. 32767
    if (idx < 256 * 128) {
        int j = idx >> 7, k = idx & 127;
        float v = (j < 128) ? W1[k * 128 + j] : W1[(128 + k) * 128 + (j - 128)];
        Wt[idx] = f2bf(v);
    }
    if (idx < 128) {
        int m = idx >> 3, tt = idx & 7;
        int jj = tt * 16 + m;
        b1p[idx] = b1[jj];
        W2p[idx] = W2[jj];
    }
}

// Kernel 2: Q[node][0:256] = z[node] @ W in bf16, permuted-store layout.
// B-RESIDENT design: wave w owns cols [w*64, w*64+64) in registers (16 short8),
// block streams 128 nodes through 8 m-tile iterations.
__global__ __launch_bounds__(256) void node_gemm(
        const float* __restrict__ z, const unsigned short* __restrict__ Wt,
        unsigned short* __restrict__ Q, int n_nodes) {
    int lane = threadIdx.x & 63;
    int wave = threadIdx.x >> 6;
    int m = lane & 15;
    int quad = lane >> 4;
    int blockBase = blockIdx.x * 128;

    // B fragments, loaded ONCE: b[t][s] for cols wave*64 + t*16 + m
    short8 b[4][4];
    #pragma unroll
    for (int t = 0; t < 4; ++t) {
        const unsigned short* wp = Wt + (size_t)(wave * 64 + t * 16 + m) * HIDDEN;
        #pragma unroll
        for (int s = 0; s < 4; ++s)
            b[t][s] = *(const short8*)(wp + s * 32 + quad * 8);
    }

    // Permuted-store coords: logical col within half = tglob*16+m, tglob=(w&1)*4+t,
    // physical pp = m*8 + tglob  (same mapping prep_wt/edge_kernel use).
    int h   = wave >> 1;
    int pp0 = m * 8 + (wave & 1) * 4;

    #pragma unroll 2
    for (int it = 0; it < 8; ++it) {
        int n0 = blockBase + it * 16;
        int row = n0 + m;

        short8 a[4];
        if (row < n_nodes) {
            const float* zp = z + (size_t)row * HIDDEN;
            #pragma unroll
            for (int s = 0; s < 4; ++s) {
                int k0 = s * 32 + quad * 8;
                float4v z0 = *(const float4v*)(zp + k0);
                float4v z1 = *(const float4v*)(zp + k0 + 4);
                short8 t;
                t[0] = (short)f2bf(z0[0]); t[1] = (short)f2bf(z0[1]);
                t[2] = (short)f2bf(z0[2]); t[3] = (short)f2bf(z0[3]);
                t[4] = (short)f2bf(z1[0]); t[5] = (short)f2bf(z1[1]);
                t[6] = (short)f2bf(z1[2]); t[7] = (short)f2bf(z1[3]);
                a[s] = t;
            }
        } else {
            #pragma unroll
            for (int s = 0; s < 4; ++s) a[s] = (short8)(0);
        }

        float4v acc[4];
        #pragma unroll
        for (int t = 0; t < 4; ++t) acc[t] = (float4v)(0.0f);

        #pragma unroll
        for (int t = 0; t < 4; ++t)
            #pragma unroll
            for (int s = 0; s < 4; ++s)
                acc[t] = __builtin_amdgcn_mfma_f32_16x16x32_bf16(a[s], b[t][s], acc[t], 0, 0, 0);

        // C/D: node-row = quad*4 + r, col-tile t. Lane writes 4 contiguous shorts.
        #pragma unroll
        for (int r = 0; r < 4; ++r) {
            int node = n0 + quad * 4 + r;
            if (node < n_nodes) {
                short4v pk;
                #pragma unroll
                for (int t = 0; t < 4; ++t) pk[t] = (short)f2bf(acc[t][r]);
                *(short4v*)(Q + (size_t)node * 256 + h * 128 + pp0) = pk;
            }
        }
    }
}

// Kernel 3: per edge e: out[e] = sum_pp relu(Q[r][pp] + Q[c][128+pp] + b1p[pp]) * W2p[pp] + b2
// 16 lanes per edge; 4 edges per lane-group to amortize uniform loads.
__global__ __launch_bounds__(256) void edge_kernel(
        const int* __restrict__ eli, const unsigned short* __restrict__ Q,
        const float* __restrict__ b1p, const float* __restrict__ W2p,
        const float* __restrict__ b2, float* __restrict__ out, int E) {
    int g      = threadIdx.x >> 4;   // group in block (0..15)
    int lane16 = threadIdx.x & 15;
    int j0 = lane16 * 8;

    float4v bA = *(const float4v*)(b1p + j0);
    float4v bB = *(const float4v*)(b1p + j0 + 4);
    float4v wA = *(const float4v*)(W2p + j0);
    float4v wB = *(const float4v*)(W2p + j0 + 4);
    float bias2 = b2[0];

    #pragma unroll
    for (int i = 0; i < 4; ++i) {
        int e = blockIdx.x * 64 + i * 16 + g;
        if (e >= E) continue;
        int r = eli[e];
        int c = eli[E + e];

        short8 u1 = *(const short8*)(Q + (size_t)r * 256 + j0);
        short8 u2 = *(const short8*)(Q + (size_t)c * 256 + 128 + j0);

        float acc = 0.0f;
        #pragma unroll
        for (int k = 0; k < 4; ++k) {
            float v = bf2f((unsigned short)u1[k]) + bf2f((unsigned short)u2[k]) + bA[k];
            v = fmaxf(v, 0.0f);
            acc = fmaf(v, wA[k], acc);
        }
        #pragma unroll
        for (int k = 0; k < 4; ++k) {
            float v = bf2f((unsigned short)u1[4 + k]) + bf2f((unsigned short)u2[4 + k]) + bB[k];
            v = fmaxf(v, 0.0f);
            acc = fmaf(v, wB[k], acc);
        }

        acc += __shfl_xor(acc, 1);
        acc += __shfl_xor(acc, 2);
        acc += __shfl_xor(acc, 4);
        acc += __shfl_xor(acc, 8);

        if (lane16 == 0) out[e] = acc + bias2;
    }
}

extern "C" void kernel_launch(void* const* d_in, const int* in_sizes, int n_in,
                              void* d_out, int out_size, void* d_ws, size_t ws_size,
                              hipStream_t stream) {
    const float* z   = (const float*)d_in[0];
    const int*   eli = (const int*)d_in[1];
    const float* W1  = (const float*)d_in[2];
    const float* b1  = (const float*)d_in[3];
    const float* W2  = (const float*)d_in[4];
    const float* b2  = (const float*)d_in[5];
    int n_nodes = in_sizes[0] / HIDDEN;       // 100000
    int E       = in_sizes[1] / 2;            // 1000000
    float* out  = (float*)d_out;

    size_t qbytes = (size_t)n_nodes * 256 * 2;
    unsigned short* Q   = (unsigned short*)d_ws;
    unsigned short* Wt  = (unsigned short*)((char*)d_ws + qbytes);
    float*          b1p = (float*)((char*)d_ws + qbytes + 256 * 128 * 2);
    float*          W2p = b1p + 128;

    prep_wt<<<128, 256, 0, stream>>>(W1, b1, W2, Wt, b1p, W2p);

    node_gemm<<<(n_nodes + 127) / 128, 256, 0, stream>>>(z, Wt, Q, n_nodes);

    edge_kernel<<<(E + 63) / 64, 256, 0, stream>>>(eli, Q, b1p, W2p, b2, out, E);
}